// Round 1
// baseline (60.995 us; speedup 1.0000x reference)
//
#include <hip/hip_runtime.h>
#include <math.h>

// FreqPSR: patch-wise FFT phase/amplitude swap attack.
// out[0 .. 25165823]            = PhaseAttack   (128,64,3,32,32) f32
// out[25165824 .. 50331647]     = AmplitudeAttack (128,64,3,32,32) f32
static constexpr int HALF_OUT = 128 * 64 * 3 * 32 * 32; // 25165824

__global__ __launch_bounds__(256) void freqpsr_kernel(
    const float* __restrict__ adv,
    const float* __restrict__ cle,
    float* __restrict__ out)
{
    // Bin-major [k][p] layout: lane=p -> stride 4B/8B, conflict-free (2 lanes/bank).
    __shared__ float2 sA   [16][64];  // adv spectrum (scratch, only needed until stage 2)
    __shared__ float2 sC   [16][64];  // clean spectrum (no-swap Z)
    __shared__ float  sCamp[16][64];  // |C|
    __shared__ float  sCpha[16][64];  // angle(C)
    __shared__ float2 sZA  [16][64];  // |C| * unit(A)  == C_amp * exp(i*A_pha)
    __shared__ float  sRatB[16][64];  // |A| / |C|      (so ratB*C == A_amp * exp(i*C_pha))

    const int blk  = blockIdx.x;      // 768 blocks = 128 b * 3 c * 2 half
    const int half = blk & 1;
    const int bc   = blk >> 1;
    const int b    = bc / 3;
    const int c    = bc % 3;
    const int tid  = threadIdx.x;

    // ---------------- Stage 1: FFT2 of every 4x4 patch (clean & adv) ----------------
    if (tid < 128) {
        const int p   = tid & 63;     // patch index (py*8+px)
        const int img = tid >> 6;     // 0 = clean, 1 = adv
        const float* src = (img ? adv : cle) + ((size_t)b * 3 + c) * 1024;
        const int py = p >> 3, px = p & 7;

        float x[4][4];
        #pragma unroll
        for (int u = 0; u < 4; ++u) {
            float4 r4 = *reinterpret_cast<const float4*>(src + (py * 4 + u) * 32 + px * 4);
            x[u][0] = r4.x; x[u][1] = r4.y; x[u][2] = r4.z; x[u][3] = r4.w;
        }
        // forward 4-pt DFT along v (real input): X1 = t1 - i*t3, X3 = t1 + i*t3
        float wr[4][4], wi[4][4]; // [u][kv]
        #pragma unroll
        for (int u = 0; u < 4; ++u) {
            float t0 = x[u][0] + x[u][2], t1 = x[u][0] - x[u][2];
            float t2 = x[u][1] + x[u][3], t3 = x[u][1] - x[u][3];
            wr[u][0] = t0 + t2; wi[u][0] = 0.0f;
            wr[u][2] = t0 - t2; wi[u][2] = 0.0f;
            wr[u][1] = t1;      wi[u][1] = -t3;
            wr[u][3] = t1;      wi[u][3] =  t3;
        }
        // forward 4-pt DFT along u (complex)
        float zr[4][4], zi[4][4]; // [ku][kv]
        #pragma unroll
        for (int kv = 0; kv < 4; ++kv) {
            float t0r = wr[0][kv] + wr[2][kv], t0i = wi[0][kv] + wi[2][kv];
            float t1r = wr[0][kv] - wr[2][kv], t1i = wi[0][kv] - wi[2][kv];
            float t2r = wr[1][kv] + wr[3][kv], t2i = wi[1][kv] + wi[3][kv];
            float t3r = wr[1][kv] - wr[3][kv], t3i = wi[1][kv] - wi[3][kv];
            zr[0][kv] = t0r + t2r; zi[0][kv] = t0i + t2i;
            zr[2][kv] = t0r - t2r; zi[2][kv] = t0i - t2i;
            // X1 = t1 - i*t3 : re = t1r + t3i, im = t1i - t3r
            zr[1][kv] = t1r + t3i; zi[1][kv] = t1i - t3r;
            zr[3][kv] = t1r - t3i; zi[3][kv] = t1i + t3r;
        }
        if (img == 0) {
            #pragma unroll
            for (int k = 0; k < 16; ++k) {
                float re = zr[k >> 2][k & 3], im = zi[k >> 2][k & 3];
                sC[k][p]    = make_float2(re, im);
                sCamp[k][p] = sqrtf(re * re + im * im);
                sCpha[k][p] = atan2f(im, re);
            }
        } else {
            #pragma unroll
            for (int k = 0; k < 16; ++k)
                sA[k][p] = make_float2(zr[k >> 2][k & 3], zi[k >> 2][k & 3]);
        }
    }
    __syncthreads();

    // ---------------- Stage 2: derived per-(patch,bin) arrays ----------------
    for (int item = tid; item < 1024; item += 256) {
        const int k = item >> 6, p = item & 63;
        float2 a = sA[k][p];
        float aamp = sqrtf(a.x * a.x + a.y * a.y);
        float camp = sCamp[k][p];
        float2 za;
        if (aamp > 0.0f) { float s = camp / aamp; za = make_float2(s * a.x, s * a.y); }
        else             { za = make_float2(camp, 0.0f); }   // exp(i*angle(0)) == 1
        sZA[k][p]   = za;
        sRatB[k][p] = (camp > 0.0f) ? (aamp / camp) : 0.0f;
    }
    __syncthreads();

    // ---------------- Stage 3: 64 attacks x {phase, amp}; this block does one half ----
    const int wave = tid >> 6;
    const int p    = tid & 63;
    const int py   = p >> 3, px = p & 7;

    for (int j = 0; j < 16; ++j) {
        const int t    = half * 64 + wave * 16 + j; // 0..127
        const int i    = t >> 1;                    // attack index
        const int type = t & 1;                     // 0 = phase attack, 1 = amplitude attack

        float zre[16], zim[16];
        if (type == 0) {
            #pragma unroll
            for (int k = 0; k < 16; ++k) {
                float own = sCpha[k][p];
                float att = sCpha[k][i];       // broadcast
                float2 cc = sC[k][p];
                float2 za = sZA[k][p];
                bool sw = (own == att);
                zre[k] = sw ? za.x : cc.x;
                zim[k] = sw ? za.y : cc.y;
            }
        } else {
            #pragma unroll
            for (int k = 0; k < 16; ++k) {
                float own = sCamp[k][p];
                float att = sCamp[k][i];       // broadcast
                float2 cc = sC[k][p];
                float r = (own == att) ? sRatB[k][p] : 1.0f;
                zre[k] = r * cc.x;
                zim[k] = r * cc.y;
            }
        }

        // inverse 4-pt DFT along kv: y1 = t1 + i*t3, y3 = t1 - i*t3
        float wr2[4][4], wi2[4][4]; // [ku][v]
        #pragma unroll
        for (int ku = 0; ku < 4; ++ku) {
            const int b0 = ku * 4;
            float t0r = zre[b0 + 0] + zre[b0 + 2], t0i = zim[b0 + 0] + zim[b0 + 2];
            float t1r = zre[b0 + 0] - zre[b0 + 2], t1i = zim[b0 + 0] - zim[b0 + 2];
            float t2r = zre[b0 + 1] + zre[b0 + 3], t2i = zim[b0 + 1] + zim[b0 + 3];
            float t3r = zre[b0 + 1] - zre[b0 + 3], t3i = zim[b0 + 1] - zim[b0 + 3];
            wr2[ku][0] = t0r + t2r; wi2[ku][0] = t0i + t2i;
            wr2[ku][2] = t0r - t2r; wi2[ku][2] = t0i - t2i;
            wr2[ku][1] = t1r - t3i; wi2[ku][1] = t1i + t3r;
            wr2[ku][3] = t1r + t3i; wi2[ku][3] = t1i - t3r;
        }
        // inverse 4-pt DFT along ku + magnitude
        float ov[4][4]; // [u][v]
        #pragma unroll
        for (int v = 0; v < 4; ++v) {
            float t0r = wr2[0][v] + wr2[2][v], t0i = wi2[0][v] + wi2[2][v];
            float t1r = wr2[0][v] - wr2[2][v], t1i = wi2[0][v] - wi2[2][v];
            float t2r = wr2[1][v] + wr2[3][v], t2i = wi2[1][v] + wi2[3][v];
            float t3r = wr2[1][v] - wr2[3][v], t3i = wi2[1][v] - wi2[3][v];
            float y0r = t0r + t2r, y0i = t0i + t2i;
            float y2r = t0r - t2r, y2i = t0i - t2i;
            float y1r = t1r - t3i, y1i = t1i + t3r;
            float y3r = t1r + t3i, y3i = t1i - t3r;
            ov[0][v] = sqrtf(y0r * y0r + y0i * y0i);
            ov[1][v] = sqrtf(y1r * y1r + y1i * y1i);
            ov[2][v] = sqrtf(y2r * y2r + y2i * y2i);
            ov[3][v] = sqrtf(y3r * y3r + y3i * y3i);
        }

        float* obase = out + (size_t)(type ? HALF_OUT : 0)
                           + ((((size_t)b * 64 + i) * 3 + c) << 10);
        #pragma unroll
        for (int u = 0; u < 4; ++u) {
            float4 w4 = make_float4(ov[u][0] * 0.0625f, ov[u][1] * 0.0625f,
                                    ov[u][2] * 0.0625f, ov[u][3] * 0.0625f);
            *reinterpret_cast<float4*>(obase + (py * 4 + u) * 32 + px * 4) = w4;
        }
    }
}

extern "C" void kernel_launch(void* const* d_in, const int* in_sizes, int n_in,
                              void* d_out, int out_size, void* d_ws, size_t ws_size,
                              hipStream_t stream) {
    const float* adv = (const float*)d_in[0];   // adver_image (128,3,32,32)
    const float* cle = (const float*)d_in[1];   // clean_image (128,3,32,32)
    float* out = (float*)d_out;                 // 2 * 128*64*3*32*32 f32
    (void)in_sizes; (void)n_in; (void)out_size; (void)d_ws; (void)ws_size;

    dim3 grid(128 * 3 * 2); // (b, c, half)
    dim3 block(256);
    freqpsr_kernel<<<grid, block, 0, stream>>>(adv, cle, out);
}

// Round 3
// 50.906 us; speedup vs baseline: 1.1982x; 1.1982x over previous
//
#include <hip/hip_runtime.h>
#include <math.h>

// FreqPSR: patch-wise FFT phase/amplitude swap attack.
// out[0 .. 25165823]        = PhaseAttack     (128,64,3,32,32) f32
// out[25165824 .. 50331647] = AmplitudeAttack (128,64,3,32,32) f32
static constexpr int HALF_OUT = 128 * 64 * 3 * 32 * 32; // 25165824

typedef float floatx4 __attribute__((ext_vector_type(4))); // native vec for nontemporal store

__global__ __launch_bounds__(256) void freqpsr_kernel(
    const float* __restrict__ adv,
    const float* __restrict__ cle,
    float* __restrict__ out)
{
    // Bin-major [k][p] layout: lane=p -> stride 4B/8B, conflict-free (2 lanes/bank).
    __shared__ float2 sA   [16][64];  // adv spectrum (scratch, consumed by stage 2)
    __shared__ float2 sC   [16][64];  // clean spectrum * 1/16 (pre-scaled for IFFT)
    __shared__ float  sCamp[16][64];  // |C|      (unscaled, for equality compare)
    __shared__ float  sCpha[16][64];  // angle(C) (for equality compare)
    __shared__ float2 sZA  [16][64];  // (|C| * unit(A)) * 1/16
    __shared__ float  sRatB[16][64];  // |A| / |C| (unitless ratio)

    const int blk  = blockIdx.x;      // 768 blocks = 128 b * 3 c * 2 type
    const int type = blk & 1;         // 0 = phase attack, 1 = amplitude attack
    const int bc   = blk >> 1;
    const int b    = bc / 3;
    const int c    = bc % 3;
    const int tid  = threadIdx.x;

    // ---------------- Stage 1: FFT2 of every 4x4 patch (clean & adv) ----------------
    if (tid < 128) {
        const int p   = tid & 63;     // patch index (py*8+px)
        const int img = tid >> 6;     // 0 = clean, 1 = adv
        const float* src = (img ? adv : cle) + ((size_t)b * 3 + c) * 1024;
        const int py = p >> 3, px = p & 7;

        float x[4][4];
        #pragma unroll
        for (int u = 0; u < 4; ++u) {
            float4 r4 = *reinterpret_cast<const float4*>(src + (py * 4 + u) * 32 + px * 4);
            x[u][0] = r4.x; x[u][1] = r4.y; x[u][2] = r4.z; x[u][3] = r4.w;
        }
        float wr[4][4], wi[4][4]; // [u][kv]
        #pragma unroll
        for (int u = 0; u < 4; ++u) {
            float t0 = x[u][0] + x[u][2], t1 = x[u][0] - x[u][2];
            float t2 = x[u][1] + x[u][3], t3 = x[u][1] - x[u][3];
            wr[u][0] = t0 + t2; wi[u][0] = 0.0f;
            wr[u][2] = t0 - t2; wi[u][2] = 0.0f;
            wr[u][1] = t1;      wi[u][1] = -t3;
            wr[u][3] = t1;      wi[u][3] =  t3;
        }
        float zr[4][4], zi[4][4]; // [ku][kv]
        #pragma unroll
        for (int kv = 0; kv < 4; ++kv) {
            float t0r = wr[0][kv] + wr[2][kv], t0i = wi[0][kv] + wi[2][kv];
            float t1r = wr[0][kv] - wr[2][kv], t1i = wi[0][kv] - wi[2][kv];
            float t2r = wr[1][kv] + wr[3][kv], t2i = wi[1][kv] + wi[3][kv];
            float t3r = wr[1][kv] - wr[3][kv], t3i = wi[1][kv] - wi[3][kv];
            zr[0][kv] = t0r + t2r; zi[0][kv] = t0i + t2i;
            zr[2][kv] = t0r - t2r; zi[2][kv] = t0i - t2i;
            zr[1][kv] = t1r + t3i; zi[1][kv] = t1i - t3r;
            zr[3][kv] = t1r - t3i; zi[3][kv] = t1i + t3r;
        }
        if (img == 0) {
            #pragma unroll
            for (int k = 0; k < 16; ++k) {
                float re = zr[k >> 2][k & 3], im = zi[k >> 2][k & 3];
                sC[k][p]    = make_float2(re * 0.0625f, im * 0.0625f);
                sCamp[k][p] = sqrtf(re * re + im * im);
                sCpha[k][p] = atan2f(im, re);
            }
        } else {
            #pragma unroll
            for (int k = 0; k < 16; ++k)
                sA[k][p] = make_float2(zr[k >> 2][k & 3], zi[k >> 2][k & 3]);
        }
    }
    __syncthreads();

    // ---------------- Stage 2: derived per-(patch,bin) arrays ----------------
    for (int item = tid; item < 1024; item += 256) {
        const int k = item >> 6, p = item & 63;
        float2 a = sA[k][p];
        float aamp = sqrtf(a.x * a.x + a.y * a.y);
        float camp = sCamp[k][p];
        float2 za;
        if (aamp > 0.0f) { float s = camp * 0.0625f / aamp; za = make_float2(s * a.x, s * a.y); }
        else             { za = make_float2(camp * 0.0625f, 0.0f); } // exp(i*angle(0)) == 1
        sZA[k][p]   = za;
        sRatB[k][p] = (camp > 0.0f) ? (aamp / camp) : 0.0f;
    }
    __syncthreads();

    // ---------------- Stage 3: this block does all 64 attacks of ONE type ----------
    const int wave = tid >> 6;
    const int p    = tid & 63;
    const int py   = p >> 3, px = p & 7;

    // Hoist all per-lane loop-invariant state into registers (only the broadcast
    // attacker value s*[k][i] varies across the j loop).
    float ccr[16], cci[16];
    #pragma unroll
    for (int k = 0; k < 16; ++k) { float2 cc = sC[k][p]; ccr[k] = cc.x; cci[k] = cc.y; }

    float* const otype = out + (size_t)(type ? HALF_OUT : 0);

    if (type == 0) { // ---------- phase attack: Z = (cpha==att) ? ZA : C ----------
        float cphar[16], zar[16], zai[16];
        #pragma unroll
        for (int k = 0; k < 16; ++k) {
            cphar[k] = sCpha[k][p];
            float2 za = sZA[k][p]; zar[k] = za.x; zai[k] = za.y;
        }
        for (int j = 0; j < 16; ++j) {
            const int i = wave * 16 + j;           // attack index 0..63
            float zre[16], zim[16];
            #pragma unroll
            for (int k = 0; k < 16; ++k) {
                float att = sCpha[k][i];           // LDS broadcast
                bool sw = (cphar[k] == att);
                zre[k] = sw ? zar[k] : ccr[k];
                zim[k] = sw ? zai[k] : cci[k];
            }
            // inverse FFT2 + magnitude
            float wr2[4][4], wi2[4][4];
            #pragma unroll
            for (int ku = 0; ku < 4; ++ku) {
                const int b0 = ku * 4;
                float t0r = zre[b0+0] + zre[b0+2], t0i = zim[b0+0] + zim[b0+2];
                float t1r = zre[b0+0] - zre[b0+2], t1i = zim[b0+0] - zim[b0+2];
                float t2r = zre[b0+1] + zre[b0+3], t2i = zim[b0+1] + zim[b0+3];
                float t3r = zre[b0+1] - zre[b0+3], t3i = zim[b0+1] - zim[b0+3];
                wr2[ku][0] = t0r + t2r; wi2[ku][0] = t0i + t2i;
                wr2[ku][2] = t0r - t2r; wi2[ku][2] = t0i - t2i;
                wr2[ku][1] = t1r - t3i; wi2[ku][1] = t1i + t3r;
                wr2[ku][3] = t1r + t3i; wi2[ku][3] = t1i - t3r;
            }
            float* obase = otype + ((((size_t)b * 64 + i) * 3 + c) << 10)
                                 + py * 128 + px * 4;
            #pragma unroll
            for (int v = 0; v < 4; ++v) {
                float t0r = wr2[0][v] + wr2[2][v], t0i = wi2[0][v] + wi2[2][v];
                float t1r = wr2[0][v] - wr2[2][v], t1i = wi2[0][v] - wi2[2][v];
                float t2r = wr2[1][v] + wr2[3][v], t2i = wi2[1][v] + wi2[3][v];
                float t3r = wr2[1][v] - wr2[3][v], t3i = wi2[1][v] - wi2[3][v];
                wr2[0][v] = sqrtf((t0r+t2r)*(t0r+t2r) + (t0i+t2i)*(t0i+t2i));
                wr2[1][v] = sqrtf((t1r-t3i)*(t1r-t3i) + (t1i+t3r)*(t1i+t3r));
                wr2[2][v] = sqrtf((t0r-t2r)*(t0r-t2r) + (t0i-t2i)*(t0i-t2i));
                wr2[3][v] = sqrtf((t1r+t3i)*(t1r+t3i) + (t1i-t3r)*(t1i-t3r));
            }
            #pragma unroll
            for (int u = 0; u < 4; ++u) {
                floatx4 w4 = { wr2[u][0], wr2[u][1], wr2[u][2], wr2[u][3] };
                __builtin_nontemporal_store(w4, reinterpret_cast<floatx4*>(obase + u * 32));
            }
        }
    } else { // ---------- amplitude attack: Z = ((camp==att) ? ratB : 1) * C ----------
        float campr[16], ratr[16];
        #pragma unroll
        for (int k = 0; k < 16; ++k) { campr[k] = sCamp[k][p]; ratr[k] = sRatB[k][p]; }
        for (int j = 0; j < 16; ++j) {
            const int i = wave * 16 + j;
            float zre[16], zim[16];
            #pragma unroll
            for (int k = 0; k < 16; ++k) {
                float att = sCamp[k][i];           // LDS broadcast
                float r = (campr[k] == att) ? ratr[k] : 1.0f;
                zre[k] = r * ccr[k];
                zim[k] = r * cci[k];
            }
            float wr2[4][4], wi2[4][4];
            #pragma unroll
            for (int ku = 0; ku < 4; ++ku) {
                const int b0 = ku * 4;
                float t0r = zre[b0+0] + zre[b0+2], t0i = zim[b0+0] + zim[b0+2];
                float t1r = zre[b0+0] - zre[b0+2], t1i = zim[b0+0] - zim[b0+2];
                float t2r = zre[b0+1] + zre[b0+3], t2i = zim[b0+1] + zim[b0+3];
                float t3r = zre[b0+1] - zre[b0+3], t3i = zim[b0+1] - zim[b0+3];
                wr2[ku][0] = t0r + t2r; wi2[ku][0] = t0i + t2i;
                wr2[ku][2] = t0r - t2r; wi2[ku][2] = t0i - t2i;
                wr2[ku][1] = t1r - t3i; wi2[ku][1] = t1i + t3r;
                wr2[ku][3] = t1r + t3i; wi2[ku][3] = t1i - t3r;
            }
            float* obase = otype + ((((size_t)b * 64 + i) * 3 + c) << 10)
                                 + py * 128 + px * 4;
            #pragma unroll
            for (int v = 0; v < 4; ++v) {
                float t0r = wr2[0][v] + wr2[2][v], t0i = wi2[0][v] + wi2[2][v];
                float t1r = wr2[0][v] - wr2[2][v], t1i = wi2[0][v] - wi2[2][v];
                float t2r = wr2[1][v] + wr2[3][v], t2i = wi2[1][v] + wi2[3][v];
                float t3r = wr2[1][v] - wr2[3][v], t3i = wi2[1][v] - wi2[3][v];
                wr2[0][v] = sqrtf((t0r+t2r)*(t0r+t2r) + (t0i+t2i)*(t0i+t2i));
                wr2[1][v] = sqrtf((t1r-t3i)*(t1r-t3i) + (t1i+t3r)*(t1i+t3r));
                wr2[2][v] = sqrtf((t0r-t2r)*(t0r-t2r) + (t0i-t2i)*(t0i-t2i));
                wr2[3][v] = sqrtf((t1r+t3i)*(t1r+t3i) + (t1i-t3r)*(t1i-t3r));
            }
            #pragma unroll
            for (int u = 0; u < 4; ++u) {
                floatx4 w4 = { wr2[u][0], wr2[u][1], wr2[u][2], wr2[u][3] };
                __builtin_nontemporal_store(w4, reinterpret_cast<floatx4*>(obase + u * 32));
            }
        }
    }
}

extern "C" void kernel_launch(void* const* d_in, const int* in_sizes, int n_in,
                              void* d_out, int out_size, void* d_ws, size_t ws_size,
                              hipStream_t stream) {
    const float* adv = (const float*)d_in[0];   // adver_image (128,3,32,32)
    const float* cle = (const float*)d_in[1];   // clean_image (128,3,32,32)
    float* out = (float*)d_out;                 // 2 * 128*64*3*32*32 f32
    (void)in_sizes; (void)n_in; (void)out_size; (void)d_ws; (void)ws_size;

    dim3 grid(128 * 3 * 2); // (b, c, type)
    dim3 block(256);
    freqpsr_kernel<<<grid, block, 0, stream>>>(adv, cle, out);
}

// Round 4
// 47.154 us; speedup vs baseline: 1.2935x; 1.0796x over previous
//
#include <hip/hip_runtime.h>
#include <math.h>

// FreqPSR: patch-wise FFT phase/amplitude swap attack.
// out[0 .. 25165823]        = PhaseAttack     (128,64,3,32,32) f32
// out[25165824 .. 50331647] = AmplitudeAttack (128,64,3,32,32) f32
static constexpr int HALF_OUT = 128 * 64 * 3 * 32 * 32; // 25165824

typedef float floatx4 __attribute__((ext_vector_type(4))); // native vec for nontemporal store

__device__ __forceinline__ float fsqrt(float x) { return __builtin_amdgcn_sqrtf(x); }
__device__ __forceinline__ float frcp(float x)  { return __builtin_amdgcn_rcpf(x); }

// IFFT2(4x4) of pre-scaled spectrum + magnitude + nontemporal store of one patch.
__device__ __forceinline__ void ifft_mag_store(const float zre[16], const float zim[16],
                                               float* __restrict__ obase) {
    float wr2[4][4], wi2[4][4];
    #pragma unroll
    for (int ku = 0; ku < 4; ++ku) {
        const int b0 = ku * 4;
        float t0r = zre[b0+0] + zre[b0+2], t0i = zim[b0+0] + zim[b0+2];
        float t1r = zre[b0+0] - zre[b0+2], t1i = zim[b0+0] - zim[b0+2];
        float t2r = zre[b0+1] + zre[b0+3], t2i = zim[b0+1] + zim[b0+3];
        float t3r = zre[b0+1] - zre[b0+3], t3i = zim[b0+1] - zim[b0+3];
        wr2[ku][0] = t0r + t2r; wi2[ku][0] = t0i + t2i;
        wr2[ku][2] = t0r - t2r; wi2[ku][2] = t0i - t2i;
        wr2[ku][1] = t1r - t3i; wi2[ku][1] = t1i + t3r;
        wr2[ku][3] = t1r + t3i; wi2[ku][3] = t1i - t3r;
    }
    #pragma unroll
    for (int v = 0; v < 4; ++v) {
        float t0r = wr2[0][v] + wr2[2][v], t0i = wi2[0][v] + wi2[2][v];
        float t1r = wr2[0][v] - wr2[2][v], t1i = wi2[0][v] - wi2[2][v];
        float t2r = wr2[1][v] + wr2[3][v], t2i = wi2[1][v] + wi2[3][v];
        float t3r = wr2[1][v] - wr2[3][v], t3i = wi2[1][v] - wi2[3][v];
        wr2[0][v] = fsqrt((t0r+t2r)*(t0r+t2r) + (t0i+t2i)*(t0i+t2i));
        wr2[1][v] = fsqrt((t1r-t3i)*(t1r-t3i) + (t1i+t3r)*(t1i+t3r));
        wr2[2][v] = fsqrt((t0r-t2r)*(t0r-t2r) + (t0i-t2i)*(t0i-t2i));
        wr2[3][v] = fsqrt((t1r+t3i)*(t1r+t3i) + (t1i-t3r)*(t1i-t3r));
    }
    #pragma unroll
    for (int u = 0; u < 4; ++u) {
        floatx4 w4 = { wr2[u][0], wr2[u][1], wr2[u][2], wr2[u][3] };
        __builtin_nontemporal_store(w4, reinterpret_cast<floatx4*>(obase + u * 32));
    }
}

__global__ __launch_bounds__(256, 3) void freqpsr_kernel(
    const float* __restrict__ adv,
    const float* __restrict__ cle,
    float* __restrict__ out)
{
    // Bin-major [k][p] layout: lane=p -> stride 4B/8B, conflict-free (2 lanes/bank).
    __shared__ float2 sA   [16][64];  // adv spectrum (scratch, consumed by stage 2)
    __shared__ float2 sC   [16][64];  // clean spectrum * 1/16 (pre-scaled for IFFT)
    __shared__ float  sCamp[16][64];  // |C|      (unscaled, for equality compare)
    __shared__ float  sCpha[16][64];  // angle(C) (for equality compare)
    __shared__ float2 sZA  [16][64];  // (|C| * unit(A)) * 1/16
    __shared__ float  sRatB[16][64];  // |A| / |C| (unitless ratio)

    const int blk  = blockIdx.x;      // 768 blocks = 128 b * 3 c * 2 type
    const int type = blk & 1;         // 0 = phase attack, 1 = amplitude attack
    const int bc   = blk >> 1;
    const int b    = bc / 3;
    const int c    = bc % 3;
    const int tid  = threadIdx.x;

    // ---------------- Stage 1: FFT2 of every 4x4 patch (clean & adv) ----------------
    if (tid < 128) {
        const int p   = tid & 63;     // patch index (py*8+px)
        const int img = tid >> 6;     // 0 = clean, 1 = adv
        const float* src = (img ? adv : cle) + ((size_t)b * 3 + c) * 1024;
        const int py = p >> 3, px = p & 7;

        float x[4][4];
        #pragma unroll
        for (int u = 0; u < 4; ++u) {
            float4 r4 = *reinterpret_cast<const float4*>(src + (py * 4 + u) * 32 + px * 4);
            x[u][0] = r4.x; x[u][1] = r4.y; x[u][2] = r4.z; x[u][3] = r4.w;
        }
        float wr[4][4], wi[4][4]; // [u][kv]
        #pragma unroll
        for (int u = 0; u < 4; ++u) {
            float t0 = x[u][0] + x[u][2], t1 = x[u][0] - x[u][2];
            float t2 = x[u][1] + x[u][3], t3 = x[u][1] - x[u][3];
            wr[u][0] = t0 + t2; wi[u][0] = 0.0f;
            wr[u][2] = t0 - t2; wi[u][2] = 0.0f;
            wr[u][1] = t1;      wi[u][1] = -t3;
            wr[u][3] = t1;      wi[u][3] =  t3;
        }
        float zr[4][4], zi[4][4]; // [ku][kv]
        #pragma unroll
        for (int kv = 0; kv < 4; ++kv) {
            float t0r = wr[0][kv] + wr[2][kv], t0i = wi[0][kv] + wi[2][kv];
            float t1r = wr[0][kv] - wr[2][kv], t1i = wi[0][kv] - wi[2][kv];
            float t2r = wr[1][kv] + wr[3][kv], t2i = wi[1][kv] + wi[3][kv];
            float t3r = wr[1][kv] - wr[3][kv], t3i = wi[1][kv] - wi[3][kv];
            zr[0][kv] = t0r + t2r; zi[0][kv] = t0i + t2i;
            zr[2][kv] = t0r - t2r; zi[2][kv] = t0i - t2i;
            zr[1][kv] = t1r + t3i; zi[1][kv] = t1i - t3r;
            zr[3][kv] = t1r - t3i; zi[3][kv] = t1i + t3r;
        }
        if (img == 0) {
            #pragma unroll
            for (int k = 0; k < 16; ++k) {
                float re = zr[k >> 2][k & 3], im = zi[k >> 2][k & 3];
                sC[k][p]    = make_float2(re * 0.0625f, im * 0.0625f);
                sCamp[k][p] = fsqrt(re * re + im * im);
                sCpha[k][p] = atan2f(im, re);
            }
        } else {
            #pragma unroll
            for (int k = 0; k < 16; ++k)
                sA[k][p] = make_float2(zr[k >> 2][k & 3], zi[k >> 2][k & 3]);
        }
    }
    __syncthreads();

    // ---------------- Stage 2: derived per-(patch,bin) arrays ----------------
    for (int item = tid; item < 1024; item += 256) {
        const int k = item >> 6, p = item & 63;
        float2 a = sA[k][p];
        float aamp = fsqrt(a.x * a.x + a.y * a.y);
        float camp = sCamp[k][p];
        float2 za;
        if (aamp > 0.0f) { float s = camp * 0.0625f * frcp(aamp); za = make_float2(s * a.x, s * a.y); }
        else             { za = make_float2(camp * 0.0625f, 0.0f); } // exp(i*angle(0)) == 1
        sZA[k][p]   = za;
        sRatB[k][p] = (camp > 0.0f) ? (aamp * frcp(camp)) : 0.0f;
    }
    __syncthreads();

    // ---------------- Stage 3: this block does all 64 attacks of ONE type ----------
    const int wave = tid >> 6;
    const int p    = tid & 63;
    const int py   = p >> 3, px = p & 7;

    // Hoist all per-lane loop-invariant state into registers (only the broadcast
    // attacker value s*[k][i] varies across the j loop).
    float ccr[16], cci[16];
    #pragma unroll
    for (int k = 0; k < 16; ++k) { float2 cc = sC[k][p]; ccr[k] = cc.x; cci[k] = cc.y; }

    float* const obase0 = out + (size_t)(type ? HALF_OUT : 0)
                              + ((((size_t)b * 64) * 3 + c) << 10)
                              + py * 128 + px * 4;

    if (type == 0) { // ---------- phase attack: Z = (cpha==att) ? ZA : C ----------
        float cphar[16], zar[16], zai[16];
        #pragma unroll
        for (int k = 0; k < 16; ++k) {
            cphar[k] = sCpha[k][p];
            float2 za = sZA[k][p]; zar[k] = za.x; zai[k] = za.y;
        }
        for (int j = 0; j < 16; ++j) {
            const int i = wave * 16 + j;           // attack index 0..63
            float zre[16], zim[16];
            #pragma unroll
            for (int k = 0; k < 16; ++k) {
                float att = sCpha[k][i];           // LDS broadcast
                bool sw = (cphar[k] == att);
                zre[k] = sw ? zar[k] : ccr[k];
                zim[k] = sw ? zai[k] : cci[k];
            }
            // bins (ku,kv) in {0,2}^2 of a real-input 4-pt FFT2 are exactly real
            // (for both C and ZA) -> literal zeros, compiler folds the IFFT.
            zim[0] = 0.0f; zim[2] = 0.0f; zim[8] = 0.0f; zim[10] = 0.0f;
            ifft_mag_store(zre, zim, obase0 + (size_t)i * 3072);
        }
    } else { // ---------- amplitude attack: Z = ((camp==att) ? ratB : 1) * C ----------
        float campr[16], ratr[16];
        #pragma unroll
        for (int k = 0; k < 16; ++k) { campr[k] = sCamp[k][p]; ratr[k] = sRatB[k][p]; }
        for (int j = 0; j < 16; ++j) {
            const int i = wave * 16 + j;
            float zre[16], zim[16];
            #pragma unroll
            for (int k = 0; k < 16; ++k) {
                float att = sCamp[k][i];           // LDS broadcast
                float r = (campr[k] == att) ? ratr[k] : 1.0f;
                zre[k] = r * ccr[k];
                zim[k] = r * cci[k];
            }
            zim[0] = 0.0f; zim[2] = 0.0f; zim[8] = 0.0f; zim[10] = 0.0f;
            ifft_mag_store(zre, zim, obase0 + (size_t)i * 3072);
        }
    }
}

extern "C" void kernel_launch(void* const* d_in, const int* in_sizes, int n_in,
                              void* d_out, int out_size, void* d_ws, size_t ws_size,
                              hipStream_t stream) {
    const float* adv = (const float*)d_in[0];   // adver_image (128,3,32,32)
    const float* cle = (const float*)d_in[1];   // clean_image (128,3,32,32)
    float* out = (float*)d_out;                 // 2 * 128*64*3*32*32 f32
    (void)in_sizes; (void)n_in; (void)out_size; (void)d_ws; (void)ws_size;

    dim3 grid(128 * 3 * 2); // (b, c, type)
    dim3 block(256);
    freqpsr_kernel<<<grid, block, 0, stream>>>(adv, cle, out);
}

// Round 5
// 45.931 us; speedup vs baseline: 1.3280x; 1.0266x over previous
//
#include <hip/hip_runtime.h>
#include <math.h>

// FreqPSR: patch-wise FFT phase/amplitude swap attack.
// out[0 .. 25165823]        = PhaseAttack     (128,64,3,32,32) f32
// out[25165824 .. 50331647] = AmplitudeAttack (128,64,3,32,32) f32
static constexpr int HALF_OUT = 128 * 64 * 3 * 32 * 32; // 25165824

typedef float floatx4 __attribute__((ext_vector_type(4))); // native vec for nontemporal store

__device__ __forceinline__ float fsqrt(float x) { return __builtin_amdgcn_sqrtf(x); }
__device__ __forceinline__ float frcp(float x)  { return __builtin_amdgcn_rcpf(x); }

// Real-output IFFT2(4x4) of a Hermitian pre-scaled spectrum + |.| + nt store.
// Only zim[1,3,4..7,9,11,12..15] are read (Hermitian rows 0,2 need no imag parts).
__device__ __forceinline__ void ifft_real_store(const float zre[16], const float zim[16],
                                                float* __restrict__ obase) {
    float gr[4][4], gi1[4], gi3[4];
    // rows ku = 0, 2 : only real g needed (gi[0],gi[2] never reach a real output)
    #pragma unroll
    for (int rr = 0; rr < 2; ++rr) {
        const int ku = rr * 2, b0 = ku * 4;
        float t0r = zre[b0+0] + zre[b0+2];
        float t1r = zre[b0+0] - zre[b0+2];
        float t2r = zre[b0+1] + zre[b0+3];
        float t3i = zim[b0+1] - zim[b0+3];
        gr[ku][0] = t0r + t2r; gr[ku][2] = t0r - t2r;
        gr[ku][1] = t1r - t3i; gr[ku][3] = t1r + t3i;
    }
    // rows ku = 1, 3 : full complex
    #pragma unroll
    for (int rr = 0; rr < 2; ++rr) {
        const int ku = rr * 2 + 1, b0 = ku * 4;
        float* gi = (rr == 0) ? gi1 : gi3;   // resolved at compile time (unrolled)
        float t0r = zre[b0+0] + zre[b0+2], t0i = zim[b0+0] + zim[b0+2];
        float t1r = zre[b0+0] - zre[b0+2], t1i = zim[b0+0] - zim[b0+2];
        float t2r = zre[b0+1] + zre[b0+3], t2i = zim[b0+1] + zim[b0+3];
        float t3r = zre[b0+1] - zre[b0+3], t3i = zim[b0+1] - zim[b0+3];
        gr[ku][0] = t0r + t2r; gi[0] = t0i + t2i;
        gr[ku][2] = t0r - t2r; gi[2] = t0i - t2i;
        gr[ku][1] = t1r - t3i; gi[1] = t1i + t3r;
        gr[ku][3] = t1r + t3i; gi[3] = t1i - t3r;
    }
    // second pass: y[u,v] = Re( sum_ku g[ku][v] * i^(ku*u) ), then |.|
    float ov[4][4];
    #pragma unroll
    for (int v = 0; v < 4; ++v) {
        float a  = gr[0][v] + gr[2][v];
        float bq = gr[0][v] - gr[2][v];
        float cq = gr[1][v] + gr[3][v];
        float e  = gi3[v] - gi1[v];
        ov[0][v] = fabsf(a + cq);
        ov[2][v] = fabsf(a - cq);
        ov[1][v] = fabsf(bq + e);
        ov[3][v] = fabsf(bq - e);
    }
    #pragma unroll
    for (int u = 0; u < 4; ++u) {
        floatx4 w4 = { ov[u][0], ov[u][1], ov[u][2], ov[u][3] };
        __builtin_nontemporal_store(w4, reinterpret_cast<floatx4*>(obase + u * 32));
    }
}

__global__ __launch_bounds__(256, 3) void freqpsr_kernel(
    const float* __restrict__ adv,
    const float* __restrict__ cle,
    float* __restrict__ out)
{
    // Bin-major [k][p] layout: lane=p -> stride 4B/8B, conflict-free (2 lanes/bank).
    __shared__ float2 sA   [16][64];  // adv spectrum (scratch, consumed by stage 2)
    __shared__ float2 sC   [16][64];  // clean spectrum * 1/16 (pre-scaled for IFFT)
    __shared__ float  sCamp[16][64];  // |C|      (unscaled, for equality compare)
    __shared__ float  sCpha[16][64];  // angle(C) (for equality compare)
    __shared__ float2 sZA  [16][64];  // (|C| * unit(A)) * 1/16
    __shared__ float  sRatB[16][64];  // |A| / |C| (unitless ratio)

    const int blk  = blockIdx.x;      // 768 blocks = 128 b * 3 c * 2 type
    const int type = blk & 1;         // 0 = phase attack, 1 = amplitude attack
    const int bc   = blk >> 1;
    const int b    = bc / 3;
    const int c    = bc % 3;
    const int tid  = threadIdx.x;

    // ---------------- Stage 1: FFT2 of every 4x4 patch (clean & adv) ----------------
    if (tid < 128) {
        const int p   = tid & 63;     // patch index (py*8+px)
        const int img = tid >> 6;     // 0 = clean, 1 = adv
        const float* src = (img ? adv : cle) + ((size_t)b * 3 + c) * 1024;
        const int py = p >> 3, px = p & 7;

        float x[4][4];
        #pragma unroll
        for (int u = 0; u < 4; ++u) {
            float4 r4 = *reinterpret_cast<const float4*>(src + (py * 4 + u) * 32 + px * 4);
            x[u][0] = r4.x; x[u][1] = r4.y; x[u][2] = r4.z; x[u][3] = r4.w;
        }
        float wr[4][4], wi[4][4]; // [u][kv]
        #pragma unroll
        for (int u = 0; u < 4; ++u) {
            float t0 = x[u][0] + x[u][2], t1 = x[u][0] - x[u][2];
            float t2 = x[u][1] + x[u][3], t3 = x[u][1] - x[u][3];
            wr[u][0] = t0 + t2; wi[u][0] = 0.0f;
            wr[u][2] = t0 - t2; wi[u][2] = 0.0f;
            wr[u][1] = t1;      wi[u][1] = -t3;
            wr[u][3] = t1;      wi[u][3] =  t3;
        }
        float zr[4][4], zi[4][4]; // [ku][kv]
        #pragma unroll
        for (int kv = 0; kv < 4; ++kv) {
            float t0r = wr[0][kv] + wr[2][kv], t0i = wi[0][kv] + wi[2][kv];
            float t1r = wr[0][kv] - wr[2][kv], t1i = wi[0][kv] - wi[2][kv];
            float t2r = wr[1][kv] + wr[3][kv], t2i = wi[1][kv] + wi[3][kv];
            float t3r = wr[1][kv] - wr[3][kv], t3i = wi[1][kv] - wi[3][kv];
            zr[0][kv] = t0r + t2r; zi[0][kv] = t0i + t2i;
            zr[2][kv] = t0r - t2r; zi[2][kv] = t0i - t2i;
            zr[1][kv] = t1r + t3i; zi[1][kv] = t1i - t3r;
            zr[3][kv] = t1r - t3i; zi[3][kv] = t1i + t3r;
        }
        if (img == 0) {
            #pragma unroll
            for (int k = 0; k < 16; ++k) {
                float re = zr[k >> 2][k & 3], im = zi[k >> 2][k & 3];
                sC[k][p]    = make_float2(re * 0.0625f, im * 0.0625f);
                sCamp[k][p] = fsqrt(re * re + im * im);
                sCpha[k][p] = atan2f(im, re);
            }
        } else {
            #pragma unroll
            for (int k = 0; k < 16; ++k)
                sA[k][p] = make_float2(zr[k >> 2][k & 3], zi[k >> 2][k & 3]);
        }
    }
    __syncthreads();

    // ---------------- Stage 2: derived per-(patch,bin) arrays ----------------
    for (int item = tid; item < 1024; item += 256) {
        const int k = item >> 6, p = item & 63;
        float2 a = sA[k][p];
        float aamp = fsqrt(a.x * a.x + a.y * a.y);
        float camp = sCamp[k][p];
        float2 za;
        if (aamp > 0.0f) { float s = camp * 0.0625f * frcp(aamp); za = make_float2(s * a.x, s * a.y); }
        else             { za = make_float2(camp * 0.0625f, 0.0f); } // exp(i*angle(0)) == 1
        sZA[k][p]   = za;
        sRatB[k][p] = (camp > 0.0f) ? (aamp * frcp(camp)) : 0.0f;
    }
    __syncthreads();

    // ---------------- Stage 3: this block does all 64 attacks of ONE type ----------
    const int wave = tid >> 6;
    const int p    = tid & 63;
    const int py   = p >> 3, px = p & 7;

    // Hoist all per-lane loop-invariant state into registers (only the broadcast
    // attacker value s*[k][i] varies across the j loop).
    float ccr[16], cci[16];
    #pragma unroll
    for (int k = 0; k < 16; ++k) { float2 cc = sC[k][p]; ccr[k] = cc.x; cci[k] = cc.y; }

    float* const obase0 = out + (size_t)(type ? HALF_OUT : 0)
                              + ((((size_t)b * 64) * 3 + c) << 10)
                              + py * 128 + px * 4;

    if (type == 0) { // ---------- phase attack: Z = (cpha==att) ? ZA : C ----------
        float cphar[16], zar[16], zai[16];
        #pragma unroll
        for (int k = 0; k < 16; ++k) {
            cphar[k] = sCpha[k][p];
            float2 za = sZA[k][p]; zar[k] = za.x; zai[k] = za.y;
        }
        for (int j = 0; j < 16; ++j) {
            const int i = wave * 16 + j;           // attack index 0..63
            float zre[16], zim[16];
            #pragma unroll
            for (int k = 0; k < 16; ++k) {
                float att = sCpha[k][i];           // LDS broadcast
                bool sw = (cphar[k] == att);
                zre[k] = sw ? zar[k] : ccr[k];
                // imag parts of the Hermitian self-conjugate bins are never read
                if (k != 0 && k != 2 && k != 8 && k != 10)
                    zim[k] = sw ? zai[k] : cci[k];
            }
            zim[0] = zim[2] = zim[8] = zim[10] = 0.0f; // dead, keeps array defined
            ifft_real_store(zre, zim, obase0 + (size_t)i * 3072);
        }
    } else { // ---------- amplitude attack: Z = ((camp==att) ? ratB : 1) * C ----------
        float campr[16], ratr[16];
        #pragma unroll
        for (int k = 0; k < 16; ++k) { campr[k] = sCamp[k][p]; ratr[k] = sRatB[k][p]; }
        for (int j = 0; j < 16; ++j) {
            const int i = wave * 16 + j;
            float zre[16], zim[16];
            #pragma unroll
            for (int k = 0; k < 16; ++k) {
                float att = sCamp[k][i];           // LDS broadcast
                float r = (campr[k] == att) ? ratr[k] : 1.0f;
                zre[k] = r * ccr[k];
                if (k != 0 && k != 2 && k != 8 && k != 10)
                    zim[k] = r * cci[k];
            }
            zim[0] = zim[2] = zim[8] = zim[10] = 0.0f;
            ifft_real_store(zre, zim, obase0 + (size_t)i * 3072);
        }
    }
}

extern "C" void kernel_launch(void* const* d_in, const int* in_sizes, int n_in,
                              void* d_out, int out_size, void* d_ws, size_t ws_size,
                              hipStream_t stream) {
    const float* adv = (const float*)d_in[0];   // adver_image (128,3,32,32)
    const float* cle = (const float*)d_in[1];   // clean_image (128,3,32,32)
    float* out = (float*)d_out;                 // 2 * 128*64*3*32*32 f32
    (void)in_sizes; (void)n_in; (void)out_size; (void)d_ws; (void)ws_size;

    dim3 grid(128 * 3 * 2); // (b, c, type)
    dim3 block(256);
    freqpsr_kernel<<<grid, block, 0, stream>>>(adv, cle, out);
}